// Round 1
// baseline (6008.833 us; speedup 1.0000x reference)
//
#include <hip/hip_runtime.h>
#include <hip/hip_bf16.h>
#include <math.h>

#define DIM 128

// ---------------- degree ----------------
__global__ __launch_bounds__(256) void deg_kernel(const int* __restrict__ dst,
                                                  unsigned* __restrict__ deg, int E) {
  int gid = blockIdx.x * 256 + threadIdx.x;
  if (gid < E) atomicAdd(&deg[dst[gid]], 1u);
}

__global__ __launch_bounds__(256) void dinv_kernel(unsigned* __restrict__ degu,
                                                   float* __restrict__ dinv, int N) {
  int gid = blockIdx.x * 256 + threadIdx.x;
  if (gid < N) {
    float d = (float)degu[gid];
    dinv[gid] = 1.0f / fmaxf(d, 1.0f);
  }
}

// ---------------- scatter 128-dim: agg[dst] += feat[src] ----------------
// one float4 per thread -> 32 threads per edge
__global__ __launch_bounds__(256) void scatter128_kernel(
    const float* __restrict__ feat, const int* __restrict__ src,
    const int* __restrict__ dst, float* __restrict__ agg, int E) {
  int gid = blockIdx.x * 256 + threadIdx.x;
  int e = gid >> 5;
  if (e >= E) return;
  int c = (gid & 31) << 2;
  int s = src[e];
  int d = dst[e];
  const float4 v = *reinterpret_cast<const float4*>(&feat[(size_t)s * DIM + c]);
  float* p = &agg[(size_t)d * DIM + c];
  unsafeAtomicAdd(p + 0, v.x);
  unsafeAtomicAdd(p + 1, v.y);
  unsafeAtomicAdd(p + 2, v.z);
  unsafeAtomicAdd(p + 3, v.w);
}

// ---------------- fused SAGE linear ----------------
// out[n][j] = relu( dinv[n] * sum_k agg[n][k]*Wl[k][j] + sum_k xin[n][k]*Wr[k][j] + b[j] )
// BM=64 rows/block, all 128 cols, K=128 in 2 tiles of 64, 2 passes (agg/Wl then xin/Wr).
// In-place (out==xin) is safe: one block owns its 64 rows across all cols; all reads
// of xin happen (into LDS/acc) before the epilogue stores.
__global__ __launch_bounds__(256) void sage_linear_kernel(
    const float* __restrict__ agg, const float* __restrict__ xin,
    const float* __restrict__ dinv, const float* __restrict__ Wl,
    const float* __restrict__ Wr, const float* __restrict__ bias,
    float* __restrict__ out, int N) {
  __shared__ float As[64][65];    // [row][k], +1 pad: conflict-free scalar reads
  __shared__ float Ws[64][128];   // [k][j]

  const int tid = threadIdx.x;
  const int bm = blockIdx.x * 64;
  const int tx = tid & 7;   // 8 col groups; cols j = 4*tx + 32*q, q=0..3 (conflict-free b128)
  const int ty = tid >> 3;  // 32 row groups of 2 rows

  float4 acc0[4], acc1[4];
#pragma unroll
  for (int q = 0; q < 4; ++q) {
    acc0[q] = make_float4(0.f, 0.f, 0.f, 0.f);
    acc1[q] = make_float4(0.f, 0.f, 0.f, 0.f);
  }

  for (int pass = 0; pass < 2; ++pass) {
    const float* A = pass ? xin : agg;
    const float* W = pass ? Wr : Wl;
    for (int kt = 0; kt < DIM; kt += 64) {
      __syncthreads();  // protect previous tile's reads
      // stage A tile: 64 rows x 64 k
      {
        const int rr = tid >> 4;          // 0..15
        const int kq = (tid & 15) << 2;   // 0..60
#pragma unroll
        for (int it = 0; it < 4; ++it) {
          int rl = rr + it * 16;
          int rg = bm + rl;
          if (rg > N - 1) rg = N - 1;
          float4 v = *reinterpret_cast<const float4*>(&A[(size_t)rg * DIM + kt + kq]);
          if (pass == 0) {
            float sc = dinv[rg];
            v.x *= sc; v.y *= sc; v.z *= sc; v.w *= sc;
          }
          As[rl][kq + 0] = v.x;
          As[rl][kq + 1] = v.y;
          As[rl][kq + 2] = v.z;
          As[rl][kq + 3] = v.w;
        }
      }
      // stage W tile: 64 k x 128 j
      {
        const int kr = tid >> 5;          // 0..7
        const int jq = (tid & 31) << 2;   // 0..124
#pragma unroll
        for (int it = 0; it < 8; ++it) {
          int kl = kr + it * 8;
          *reinterpret_cast<float4*>(&Ws[kl][jq]) =
              *reinterpret_cast<const float4*>(&W[(size_t)(kt + kl) * DIM + jq]);
        }
      }
      __syncthreads();
      const int r0 = ty * 2;
#pragma unroll 8
      for (int kk = 0; kk < 64; ++kk) {
        float a0 = As[r0][kk];
        float a1 = As[r0 + 1][kk];
#pragma unroll
        for (int q = 0; q < 4; ++q) {
          float4 w = *reinterpret_cast<const float4*>(&Ws[kk][tx * 4 + q * 32]);
          acc0[q].x += a0 * w.x; acc0[q].y += a0 * w.y;
          acc0[q].z += a0 * w.z; acc0[q].w += a0 * w.w;
          acc1[q].x += a1 * w.x; acc1[q].y += a1 * w.y;
          acc1[q].z += a1 * w.z; acc1[q].w += a1 * w.w;
        }
      }
    }
  }

  // epilogue: bias + relu + store
  float4 bv[4];
#pragma unroll
  for (int q = 0; q < 4; ++q)
    bv[q] = *reinterpret_cast<const float4*>(&bias[tx * 4 + q * 32]);
  const int r0g = bm + ty * 2;
#pragma unroll
  for (int ri = 0; ri < 2; ++ri) {
    int rg = r0g + ri;
    if (rg < N) {
      float4* accp = ri ? acc1 : acc0;
#pragma unroll
      for (int q = 0; q < 4; ++q) {
        float4 o;
        o.x = fmaxf(accp[q].x + bv[q].x, 0.f);
        o.y = fmaxf(accp[q].y + bv[q].y, 0.f);
        o.z = fmaxf(accp[q].z + bv[q].z, 0.f);
        o.w = fmaxf(accp[q].w + bv[q].w, 0.f);
        *reinterpret_cast<float4*>(&out[(size_t)rg * DIM + tx * 4 + q * 32]) = o;
      }
    }
  }
}

// ---------------- layer 3 small GEMM: y[n][0..1]=h@W3l, y[n][2..3]=h@W3r ----------------
__global__ __launch_bounds__(256) void lin3_kernel(
    const float* __restrict__ h, const float* __restrict__ W3l,
    const float* __restrict__ W3r, float* __restrict__ y, int N) {
  __shared__ float Wc[DIM][4];
  int tid = threadIdx.x;
  if (tid < DIM) {
    Wc[tid][0] = W3l[tid * 2 + 0];
    Wc[tid][1] = W3l[tid * 2 + 1];
    Wc[tid][2] = W3r[tid * 2 + 0];
    Wc[tid][3] = W3r[tid * 2 + 1];
  }
  __syncthreads();
  int gid = blockIdx.x * 256 + tid;
  int n = gid >> 2, j = gid & 3;
  if (n >= N) return;
  const float* row = &h[(size_t)n * DIM];
  float s = 0.f;
#pragma unroll 8
  for (int k4 = 0; k4 < DIM / 4; ++k4) {
    float4 hv = *reinterpret_cast<const float4*>(&row[k4 * 4]);
    s += hv.x * Wc[k4 * 4 + 0][j] + hv.y * Wc[k4 * 4 + 1][j] +
         hv.z * Wc[k4 * 4 + 2][j] + hv.w * Wc[k4 * 4 + 3][j];
  }
  y[gid] = s;
}

// ---------------- scatter 2-dim (layer 3, post-GEMM thanks to linearity) ----------------
__global__ __launch_bounds__(256) void scatter2_kernel(
    const float* __restrict__ y, const int* __restrict__ src,
    const int* __restrict__ dst, float* __restrict__ agg3, int E) {
  int gid = blockIdx.x * 256 + threadIdx.x;
  if (gid >= E) return;
  int s = src[gid], d = dst[gid];
  float2 v = *reinterpret_cast<const float2*>(&y[(size_t)s * 4]);
  unsafeAtomicAdd(&agg3[(size_t)d * 2 + 0], v.x);
  unsafeAtomicAdd(&agg3[(size_t)d * 2 + 1], v.y);
}

// ---------------- finalize: relu + 2-class log_softmax ----------------
__global__ __launch_bounds__(256) void finalize_kernel(
    const float* __restrict__ agg3, const float* __restrict__ y,
    const float* __restrict__ dinv, const float* __restrict__ b3,
    float* __restrict__ out, int N) {
  int n = blockIdx.x * 256 + threadIdx.x;
  if (n >= N) return;
  float di = dinv[n];
  float o0 = fmaxf(agg3[n * 2 + 0] * di + y[n * 4 + 2] + b3[0], 0.f);
  float o1 = fmaxf(agg3[n * 2 + 1] * di + y[n * 4 + 3] + b3[1], 0.f);
  float m = fmaxf(o0, o1);
  float l = m + logf(expf(o0 - m) + expf(o1 - m));
  out[n * 2 + 0] = o0 - l;
  out[n * 2 + 1] = o1 - l;
}

extern "C" void kernel_launch(void* const* d_in, const int* in_sizes, int n_in,
                              void* d_out, int out_size, void* d_ws, size_t ws_size,
                              hipStream_t stream) {
  const float* x   = (const float*)d_in[0];
  const int*   ei  = (const int*)d_in[1];
  const float* W1l = (const float*)d_in[2];
  const float* W1r = (const float*)d_in[3];
  const float* b1  = (const float*)d_in[4];
  const float* W2l = (const float*)d_in[5];
  const float* W2r = (const float*)d_in[6];
  const float* b2  = (const float*)d_in[7];
  const float* W3l = (const float*)d_in[8];
  const float* W3r = (const float*)d_in[9];
  const float* b3  = (const float*)d_in[10];

  const int N = in_sizes[0] / DIM;  // 100000
  const int E = in_sizes[1] / 2;    // 1600000
  const int* src = ei;
  const int* dst = ei + E;

  char* ws = (char*)d_ws;
  size_t off = 0;
  auto alloc = [&](size_t bytes) {
    void* p = ws + off;
    off = (off + bytes + 255) & ~(size_t)255;
    return p;
  };
  float* dinv = (float*)alloc((size_t)N * 4);
  float* agg  = (float*)alloc((size_t)N * DIM * 4);
  float* h    = (float*)alloc((size_t)N * DIM * 4);
  float* y    = (float*)alloc((size_t)N * 4 * 4);
  float* agg3 = (float*)alloc((size_t)N * 2 * 4);

  // degrees
  hipMemsetAsync(dinv, 0, (size_t)N * 4, stream);
  deg_kernel<<<(E + 255) / 256, 256, 0, stream>>>(dst, (unsigned*)dinv, E);
  dinv_kernel<<<(N + 255) / 256, 256, 0, stream>>>((unsigned*)dinv, dinv, N);

  // layer 1: h = relu(dinv*scatter(x) @ W1l + x @ W1r + b1)
  hipMemsetAsync(agg, 0, (size_t)N * DIM * 4, stream);
  scatter128_kernel<<<(E * 32 + 255) / 256, 256, 0, stream>>>(x, src, dst, agg, E);
  sage_linear_kernel<<<(N + 63) / 64, 256, 0, stream>>>(agg, x, dinv, W1l, W1r, b1, h, N);

  // layer 2: h = relu(dinv*scatter(h) @ W2l + h @ W2r + b2)   (GEMM in-place on h)
  hipMemsetAsync(agg, 0, (size_t)N * DIM * 4, stream);
  scatter128_kernel<<<(E * 32 + 255) / 256, 256, 0, stream>>>(h, src, dst, agg, E);
  sage_linear_kernel<<<(N + 63) / 64, 256, 0, stream>>>(agg, h, dinv, W2l, W2r, b2, h, N);

  // layer 3: y = h @ [W3l | W3r]; scatter only the 2-dim lin_l product
  lin3_kernel<<<(N * 4 + 255) / 256, 256, 0, stream>>>(h, W3l, W3r, y, N);
  hipMemsetAsync(agg3, 0, (size_t)N * 2 * 4, stream);
  scatter2_kernel<<<(E + 255) / 256, 256, 0, stream>>>(y, src, dst, agg3, E);
  finalize_kernel<<<(N + 255) / 256, 256, 0, stream>>>(agg3, y, dinv, b3, (float*)d_out, N);
}

// Round 2
// 810.353 us; speedup vs baseline: 7.4151x; 7.4151x over previous
//
#include <hip/hip_runtime.h>
#include <hip/hip_bf16.h>
#include <math.h>

#define DIM 128

// ---------------- degree histogram ----------------
__global__ __launch_bounds__(256) void hist_kernel(const int* __restrict__ dst,
                                                   unsigned* __restrict__ deg, int E) {
  int gid = blockIdx.x * 256 + threadIdx.x;
  if (gid < E) atomicAdd(&deg[dst[gid]], 1u);
}

__global__ __launch_bounds__(256) void dinv_kernel(const unsigned* __restrict__ deg,
                                                   float* __restrict__ dinv, int N) {
  int gid = blockIdx.x * 256 + threadIdx.x;
  if (gid < N) {
    float d = (float)deg[gid];
    dinv[gid] = 1.0f / fmaxf(d, 1.0f);
  }
}

// ---------------- two-level exclusive scan over deg ----------------
__global__ __launch_bounds__(256) void scan_block_kernel(const unsigned* __restrict__ deg,
                                                         unsigned* __restrict__ excl,
                                                         unsigned* __restrict__ partial, int N) {
  __shared__ unsigned s[256];
  int i = blockIdx.x * 256 + threadIdx.x;
  unsigned v = (i < N) ? deg[i] : 0u;
  s[threadIdx.x] = v;
  __syncthreads();
#pragma unroll
  for (int d = 1; d < 256; d <<= 1) {
    unsigned t = (threadIdx.x >= d) ? s[threadIdx.x - d] : 0u;
    __syncthreads();
    s[threadIdx.x] += t;
    __syncthreads();
  }
  if (i < N) excl[i] = s[threadIdx.x] - v;  // exclusive within block
  if (threadIdx.x == 255) partial[blockIdx.x] = s[255];
}

__global__ __launch_bounds__(256) void scan_partials_kernel(unsigned* __restrict__ partial, int B) {
  __shared__ unsigned s[256];
  __shared__ unsigned carry;
  if (threadIdx.x == 0) carry = 0u;
  __syncthreads();
  for (int base = 0; base < B; base += 256) {
    int i = base + threadIdx.x;
    unsigned v = (i < B) ? partial[i] : 0u;
    s[threadIdx.x] = v;
    __syncthreads();
#pragma unroll
    for (int d = 1; d < 256; d <<= 1) {
      unsigned t = (threadIdx.x >= d) ? s[threadIdx.x - d] : 0u;
      __syncthreads();
      s[threadIdx.x] += t;
      __syncthreads();
    }
    if (i < B) partial[i] = carry + s[threadIdx.x] - v;  // exclusive
    __syncthreads();
    if (threadIdx.x == 0) carry += s[255];
    __syncthreads();
  }
}

__global__ __launch_bounds__(256) void add_offsets_kernel(const unsigned* __restrict__ excl,
                                                          const unsigned* __restrict__ partial,
                                                          unsigned* __restrict__ off, int N, int E) {
  int i = blockIdx.x * 256 + threadIdx.x;
  if (i < N) off[i] = excl[i] + partial[i >> 8];
  if (i == N) off[N] = (unsigned)E;
}

// ---------------- CSR fill: bucket src ids by dst ----------------
__global__ __launch_bounds__(256) void csr_fill_kernel(const int* __restrict__ src,
                                                       const int* __restrict__ dst,
                                                       const unsigned* __restrict__ off,
                                                       unsigned* __restrict__ cursor,
                                                       int* __restrict__ csr_src, int E) {
  int e = blockIdx.x * 256 + threadIdx.x;
  if (e >= E) return;
  int d = dst[e];
  unsigned p = off[d] + atomicAdd(&cursor[d], 1u);
  csr_src[p] = src[e];
}

// ---------------- gather-aggregate: agg[n] = dinv[n] * sum_{e in csr(n)} feat[src_e] ----------------
// 32 lanes per node (each owns a float4 column slice), 8 nodes per 256-block
__global__ __launch_bounds__(256) void gather_agg_kernel(const float* __restrict__ feat,
                                                         const int* __restrict__ csr_src,
                                                         const unsigned* __restrict__ off,
                                                         const float* __restrict__ dinv,
                                                         float* __restrict__ agg, int N) {
  int node = blockIdx.x * 8 + (threadIdx.x >> 5);
  if (node >= N) return;
  int lane = threadIdx.x & 31;
  unsigned beg = off[node], end = off[node + 1];
  float4 acc = make_float4(0.f, 0.f, 0.f, 0.f);
  for (unsigned e = beg; e < end; ++e) {
    int s = csr_src[e];
    float4 v = *reinterpret_cast<const float4*>(&feat[(size_t)s * DIM + lane * 4]);
    acc.x += v.x; acc.y += v.y; acc.z += v.z; acc.w += v.w;
  }
  float di = dinv[node];
  acc.x *= di; acc.y *= di; acc.z *= di; acc.w *= di;
  *reinterpret_cast<float4*>(&agg[(size_t)node * DIM + lane * 4]) = acc;
}

// ---------------- fused SAGE linear ----------------
// out[n][j] = relu( sum_k agg[n][k]*Wl[k][j] + sum_k xin[n][k]*Wr[k][j] + b[j] )
// (agg is already mean-normalized by the gather kernel)
__global__ __launch_bounds__(256) void sage_linear_kernel(
    const float* __restrict__ agg, const float* __restrict__ xin,
    const float* __restrict__ Wl, const float* __restrict__ Wr,
    const float* __restrict__ bias, float* __restrict__ out, int N) {
  __shared__ float As[64][65];
  __shared__ float Ws[64][128];

  const int tid = threadIdx.x;
  const int bm = blockIdx.x * 64;
  const int tx = tid & 7;
  const int ty = tid >> 3;

  float4 acc0[4], acc1[4];
#pragma unroll
  for (int q = 0; q < 4; ++q) {
    acc0[q] = make_float4(0.f, 0.f, 0.f, 0.f);
    acc1[q] = make_float4(0.f, 0.f, 0.f, 0.f);
  }

  for (int pass = 0; pass < 2; ++pass) {
    const float* A = pass ? xin : agg;
    const float* W = pass ? Wr : Wl;
    for (int kt = 0; kt < DIM; kt += 64) {
      __syncthreads();
      {
        const int rr = tid >> 4;
        const int kq = (tid & 15) << 2;
#pragma unroll
        for (int it = 0; it < 4; ++it) {
          int rl = rr + it * 16;
          int rg = bm + rl;
          if (rg > N - 1) rg = N - 1;
          float4 v = *reinterpret_cast<const float4*>(&A[(size_t)rg * DIM + kt + kq]);
          As[rl][kq + 0] = v.x;
          As[rl][kq + 1] = v.y;
          As[rl][kq + 2] = v.z;
          As[rl][kq + 3] = v.w;
        }
      }
      {
        const int kr = tid >> 5;
        const int jq = (tid & 31) << 2;
#pragma unroll
        for (int it = 0; it < 8; ++it) {
          int kl = kr + it * 8;
          *reinterpret_cast<float4*>(&Ws[kl][jq]) =
              *reinterpret_cast<const float4*>(&W[(size_t)(kt + kl) * DIM + jq]);
        }
      }
      __syncthreads();
      const int r0 = ty * 2;
#pragma unroll 8
      for (int kk = 0; kk < 64; ++kk) {
        float a0 = As[r0][kk];
        float a1 = As[r0 + 1][kk];
#pragma unroll
        for (int q = 0; q < 4; ++q) {
          float4 w = *reinterpret_cast<const float4*>(&Ws[kk][tx * 4 + q * 32]);
          acc0[q].x += a0 * w.x; acc0[q].y += a0 * w.y;
          acc0[q].z += a0 * w.z; acc0[q].w += a0 * w.w;
          acc1[q].x += a1 * w.x; acc1[q].y += a1 * w.y;
          acc1[q].z += a1 * w.z; acc1[q].w += a1 * w.w;
        }
      }
    }
  }

  float4 bv[4];
#pragma unroll
  for (int q = 0; q < 4; ++q)
    bv[q] = *reinterpret_cast<const float4*>(&bias[tx * 4 + q * 32]);
  const int r0g = bm + ty * 2;
#pragma unroll
  for (int ri = 0; ri < 2; ++ri) {
    int rg = r0g + ri;
    if (rg < N) {
      float4* accp = ri ? acc1 : acc0;
#pragma unroll
      for (int q = 0; q < 4; ++q) {
        float4 o;
        o.x = fmaxf(accp[q].x + bv[q].x, 0.f);
        o.y = fmaxf(accp[q].y + bv[q].y, 0.f);
        o.z = fmaxf(accp[q].z + bv[q].z, 0.f);
        o.w = fmaxf(accp[q].w + bv[q].w, 0.f);
        *reinterpret_cast<float4*>(&out[(size_t)rg * DIM + tx * 4 + q * 32]) = o;
      }
    }
  }
}

// ---------------- layer 3 small GEMM: y[n][0..1]=h@W3l, y[n][2..3]=h@W3r ----------------
__global__ __launch_bounds__(256) void lin3_kernel(
    const float* __restrict__ h, const float* __restrict__ W3l,
    const float* __restrict__ W3r, float* __restrict__ y, int N) {
  __shared__ float Wc[DIM][4];
  int tid = threadIdx.x;
  if (tid < DIM) {
    Wc[tid][0] = W3l[tid * 2 + 0];
    Wc[tid][1] = W3l[tid * 2 + 1];
    Wc[tid][2] = W3r[tid * 2 + 0];
    Wc[tid][3] = W3r[tid * 2 + 1];
  }
  __syncthreads();
  int gid = blockIdx.x * 256 + tid;
  int n = gid >> 2, j = gid & 3;
  if (n >= N) return;
  const float* row = &h[(size_t)n * DIM];
  float s = 0.f;
#pragma unroll 8
  for (int k4 = 0; k4 < DIM / 4; ++k4) {
    float4 hv = *reinterpret_cast<const float4*>(&row[k4 * 4]);
    s += hv.x * Wc[k4 * 4 + 0][j] + hv.y * Wc[k4 * 4 + 1][j] +
         hv.z * Wc[k4 * 4 + 2][j] + hv.w * Wc[k4 * 4 + 3][j];
  }
  y[gid] = s;
}

// ---------------- layer 3: CSR gather of 2-dim messages + bias + relu + log_softmax ----------------
__global__ __launch_bounds__(256) void final3_kernel(const float* __restrict__ y,
                                                     const int* __restrict__ csr_src,
                                                     const unsigned* __restrict__ off,
                                                     const float* __restrict__ dinv,
                                                     const float* __restrict__ b3,
                                                     float* __restrict__ out, int N) {
  int n = blockIdx.x * 256 + threadIdx.x;
  if (n >= N) return;
  unsigned beg = off[n], end = off[n + 1];
  float s0 = 0.f, s1 = 0.f;
  for (unsigned e = beg; e < end; ++e) {
    int s = csr_src[e];
    float2 v = *reinterpret_cast<const float2*>(&y[(size_t)s * 4]);
    s0 += v.x; s1 += v.y;
  }
  float di = dinv[n];
  float o0 = fmaxf(s0 * di + y[(size_t)n * 4 + 2] + b3[0], 0.f);
  float o1 = fmaxf(s1 * di + y[(size_t)n * 4 + 3] + b3[1], 0.f);
  float m = fmaxf(o0, o1);
  float l = m + logf(expf(o0 - m) + expf(o1 - m));
  out[n * 2 + 0] = o0 - l;
  out[n * 2 + 1] = o1 - l;
}

extern "C" void kernel_launch(void* const* d_in, const int* in_sizes, int n_in,
                              void* d_out, int out_size, void* d_ws, size_t ws_size,
                              hipStream_t stream) {
  const float* x   = (const float*)d_in[0];
  const int*   ei  = (const int*)d_in[1];
  const float* W1l = (const float*)d_in[2];
  const float* W1r = (const float*)d_in[3];
  const float* b1  = (const float*)d_in[4];
  const float* W2l = (const float*)d_in[5];
  const float* W2r = (const float*)d_in[6];
  const float* b2  = (const float*)d_in[7];
  const float* W3l = (const float*)d_in[8];
  const float* W3r = (const float*)d_in[9];
  const float* b3  = (const float*)d_in[10];

  const int N = in_sizes[0] / DIM;  // 100000
  const int E = in_sizes[1] / 2;    // 1600000
  const int* src = ei;
  const int* dst = ei + E;
  const int B = (N + 255) / 256;    // scan blocks

  char* ws = (char*)d_ws;
  size_t off_b = 0;
  auto alloc = [&](size_t bytes) {
    void* p = ws + off_b;
    off_b = (off_b + bytes + 255) & ~(size_t)255;
    return p;
  };
  unsigned* deg     = (unsigned*)alloc((size_t)N * 4);
  unsigned* excl    = (unsigned*)alloc((size_t)N * 4);   // reused as cursor after add_offsets
  unsigned* partial = (unsigned*)alloc((size_t)B * 4);
  unsigned* offs    = (unsigned*)alloc((size_t)(N + 1) * 4);
  int*      csr_src = (int*)alloc((size_t)E * 4);
  float*    dinv    = (float*)alloc((size_t)N * 4);
  float*    agg     = (float*)alloc((size_t)N * DIM * 4);
  float*    h       = (float*)alloc((size_t)N * DIM * 4);
  float*    y       = (float*)alloc((size_t)N * 4 * 4);

  // ---- CSR build ----
  hipMemsetAsync(deg, 0, (size_t)N * 4, stream);
  hist_kernel<<<(E + 255) / 256, 256, 0, stream>>>(dst, deg, E);
  dinv_kernel<<<(N + 255) / 256, 256, 0, stream>>>(deg, dinv, N);
  scan_block_kernel<<<B, 256, 0, stream>>>(deg, excl, partial, N);
  scan_partials_kernel<<<1, 256, 0, stream>>>(partial, B);
  add_offsets_kernel<<<(N + 256) / 256, 256, 0, stream>>>(excl, partial, offs, N, E);
  unsigned* cursor = excl;  // excl dead after add_offsets
  hipMemsetAsync(cursor, 0, (size_t)N * 4, stream);
  csr_fill_kernel<<<(E + 255) / 256, 256, 0, stream>>>(src, dst, offs, cursor, csr_src, E);

  // ---- layer 1 ----
  gather_agg_kernel<<<(N + 7) / 8, 256, 0, stream>>>(x, csr_src, offs, dinv, agg, N);
  sage_linear_kernel<<<(N + 63) / 64, 256, 0, stream>>>(agg, x, W1l, W1r, b1, h, N);

  // ---- layer 2 (GEMM in-place on h) ----
  gather_agg_kernel<<<(N + 7) / 8, 256, 0, stream>>>(h, csr_src, offs, dinv, agg, N);
  sage_linear_kernel<<<(N + 63) / 64, 256, 0, stream>>>(agg, h, W2l, W2r, b2, h, N);

  // ---- layer 3 ----
  lin3_kernel<<<(N * 4 + 255) / 256, 256, 0, stream>>>(h, W3l, W3r, y, N);
  final3_kernel<<<(N + 255) / 256, 256, 0, stream>>>(y, csr_src, offs, dinv, b3, (float*)d_out, N);
}

// Round 3
// 530.832 us; speedup vs baseline: 11.3196x; 1.5266x over previous
//
#include <hip/hip_runtime.h>
#include <hip/hip_bf16.h>
#include <math.h>

#define DIM 128

typedef __attribute__((ext_vector_type(8))) short bf16x8;
typedef __attribute__((ext_vector_type(4))) float f32x4;

__device__ __forceinline__ ushort f2bf(float f) {  // RTNE
  unsigned u = __float_as_uint(f);
  return (ushort)((u + 0x7FFFu + ((u >> 16) & 1u)) >> 16);
}
__device__ __forceinline__ float bf2f(ushort h) {
  return __uint_as_float(((unsigned)h) << 16);
}

// ---------------- degree histogram ----------------
__global__ __launch_bounds__(256) void hist_kernel(const int* __restrict__ dst,
                                                   unsigned* __restrict__ deg, int E) {
  int gid = blockIdx.x * 256 + threadIdx.x;
  if (gid < E) atomicAdd(&deg[dst[gid]], 1u);
}

__global__ __launch_bounds__(256) void dinv_kernel(const unsigned* __restrict__ deg,
                                                   float* __restrict__ dinv, int N) {
  int gid = blockIdx.x * 256 + threadIdx.x;
  if (gid < N) {
    float d = (float)deg[gid];
    dinv[gid] = 1.0f / fmaxf(d, 1.0f);
  }
}

// ---------------- two-level exclusive scan over deg ----------------
__global__ __launch_bounds__(256) void scan_block_kernel(const unsigned* __restrict__ deg,
                                                         unsigned* __restrict__ excl,
                                                         unsigned* __restrict__ partial, int N) {
  __shared__ unsigned s[256];
  int i = blockIdx.x * 256 + threadIdx.x;
  unsigned v = (i < N) ? deg[i] : 0u;
  s[threadIdx.x] = v;
  __syncthreads();
#pragma unroll
  for (int d = 1; d < 256; d <<= 1) {
    unsigned t = (threadIdx.x >= d) ? s[threadIdx.x - d] : 0u;
    __syncthreads();
    s[threadIdx.x] += t;
    __syncthreads();
  }
  if (i < N) excl[i] = s[threadIdx.x] - v;
  if (threadIdx.x == 255) partial[blockIdx.x] = s[255];
}

__global__ __launch_bounds__(256) void scan_partials_kernel(unsigned* __restrict__ partial, int B) {
  __shared__ unsigned s[256];
  __shared__ unsigned carry;
  if (threadIdx.x == 0) carry = 0u;
  __syncthreads();
  for (int base = 0; base < B; base += 256) {
    int i = base + threadIdx.x;
    unsigned v = (i < B) ? partial[i] : 0u;
    s[threadIdx.x] = v;
    __syncthreads();
#pragma unroll
    for (int d = 1; d < 256; d <<= 1) {
      unsigned t = (threadIdx.x >= d) ? s[threadIdx.x - d] : 0u;
      __syncthreads();
      s[threadIdx.x] += t;
      __syncthreads();
    }
    if (i < B) partial[i] = carry + s[threadIdx.x] - v;
    __syncthreads();
    if (threadIdx.x == 0) carry += s[255];
    __syncthreads();
  }
}

__global__ __launch_bounds__(256) void add_offsets_kernel(const unsigned* __restrict__ excl,
                                                          const unsigned* __restrict__ partial,
                                                          unsigned* __restrict__ off, int N, int E) {
  int i = blockIdx.x * 256 + threadIdx.x;
  if (i < N) off[i] = excl[i] + partial[i >> 8];
  if (i == N) off[N] = (unsigned)E;
}

// ---------------- CSR fill ----------------
__global__ __launch_bounds__(256) void csr_fill_kernel(const int* __restrict__ src,
                                                       const int* __restrict__ dst,
                                                       const unsigned* __restrict__ off,
                                                       unsigned* __restrict__ cursor,
                                                       int* __restrict__ csr_src, int E) {
  int e = blockIdx.x * 256 + threadIdx.x;
  if (e >= E) return;
  int d = dst[e];
  unsigned p = off[d] + atomicAdd(&cursor[d], 1u);
  csr_src[p] = src[e];
}

// ---------------- fp32 -> bf16 hi/lo split ----------------
__global__ __launch_bounds__(256) void split_kernel(const float* __restrict__ x,
                                                    ushort* __restrict__ xh,
                                                    ushort* __restrict__ xl, long total) {
  long i = ((long)blockIdx.x * 256 + threadIdx.x) * 4;
  if (i >= total) return;
  float4 v = *(const float4*)(x + i);
  ushort h0 = f2bf(v.x), h1 = f2bf(v.y), h2 = f2bf(v.z), h3 = f2bf(v.w);
  ushort l0 = f2bf(v.x - bf2f(h0)), l1 = f2bf(v.y - bf2f(h1));
  ushort l2 = f2bf(v.z - bf2f(h2)), l3 = f2bf(v.w - bf2f(h3));
  uint2 H, L;
  H.x = (unsigned)h0 | ((unsigned)h1 << 16);
  H.y = (unsigned)h2 | ((unsigned)h3 << 16);
  L.x = (unsigned)l0 | ((unsigned)l1 << 16);
  L.y = (unsigned)l2 | ((unsigned)l3 << 16);
  *(uint2*)(xh + i) = H;
  *(uint2*)(xl + i) = L;
}

// ---------------- W fp32 [k][n] -> transposed bf16 hi/lo tables [n][k] ----------------
// wtabs layout: matrix m in {W1l,W1r,W2l,W2r}: H at m*32768, L at m*32768+16384
__global__ __launch_bounds__(256) void wsplit_kernel(const float* __restrict__ W1l,
                                                     const float* __restrict__ W1r,
                                                     const float* __restrict__ W2l,
                                                     const float* __restrict__ W2r,
                                                     ushort* __restrict__ tabs) {
  int m = blockIdx.y;
  const float* W = (m == 0) ? W1l : (m == 1) ? W1r : (m == 2) ? W2l : W2r;
  ushort* H = tabs + (size_t)m * 32768;
  ushort* L = H + 16384;
  int idx = blockIdx.x * 256 + threadIdx.x;  // 0..16383
  int k = idx >> 7, n = idx & 127;
  float v = W[idx];
  ushort h = f2bf(v);
  H[n * DIM + k] = h;
  L[n * DIM + k] = f2bf(v - bf2f(h));
}

// ---------------- gather-aggregate from bf16 hi table; emit agg hi/lo ----------------
// 16 lanes/node, 8 bf16 (16B) per lane, 16 nodes per 256-block
__global__ __launch_bounds__(256) void gather_bf16_kernel(
    const ushort* __restrict__ featH, const int* __restrict__ csr_src,
    const unsigned* __restrict__ off, const float* __restrict__ dinv,
    ushort* __restrict__ aggH, ushort* __restrict__ aggL, int N) {
  int node = blockIdx.x * 16 + (threadIdx.x >> 4);
  if (node >= N) return;
  int lane = threadIdx.x & 15;
  unsigned beg = off[node], end = off[node + 1];
  float acc[8];
#pragma unroll
  for (int t = 0; t < 8; ++t) acc[t] = 0.f;
  for (unsigned e = beg; e < end; ++e) {
    int s = csr_src[e];
    int4 v = *(const int4*)(featH + (size_t)s * DIM + lane * 8);
    unsigned w0 = (unsigned)v.x, w1 = (unsigned)v.y, w2 = (unsigned)v.z, w3 = (unsigned)v.w;
    acc[0] += __uint_as_float(w0 << 16);
    acc[1] += __uint_as_float(w0 & 0xFFFF0000u);
    acc[2] += __uint_as_float(w1 << 16);
    acc[3] += __uint_as_float(w1 & 0xFFFF0000u);
    acc[4] += __uint_as_float(w2 << 16);
    acc[5] += __uint_as_float(w2 & 0xFFFF0000u);
    acc[6] += __uint_as_float(w3 << 16);
    acc[7] += __uint_as_float(w3 & 0xFFFF0000u);
  }
  float di = dinv[node];
  unsigned ph[4], pl[4];
#pragma unroll
  for (int t = 0; t < 4; ++t) {
    float f0 = acc[2 * t] * di, f1 = acc[2 * t + 1] * di;
    ushort h0 = f2bf(f0), h1 = f2bf(f1);
    ushort l0 = f2bf(f0 - bf2f(h0)), l1 = f2bf(f1 - bf2f(h1));
    ph[t] = (unsigned)h0 | ((unsigned)h1 << 16);
    pl[t] = (unsigned)l0 | ((unsigned)l1 << 16);
  }
  size_t o = (size_t)node * DIM + lane * 8;
  *(int4*)(aggH + o) = make_int4((int)ph[0], (int)ph[1], (int)ph[2], (int)ph[3]);
  *(int4*)(aggL + o) = make_int4((int)pl[0], (int)pl[1], (int)pl[2], (int)pl[3]);
}

// ---------------- MFMA SAGE layer ----------------
// out = relu( (aggH+aggL)@Wl + (xH+xL)@Wr + b ) via 6 bf16 segments:
//   aggH@WlH + aggL@WlH + aggH@WlL + xH@WrH + xL@WrH + xH@WrL   (lo@lo dropped, ~2^-18)
// 128x128 tile, 4 waves x 64x64 quadrants, BK=64, XOR-swizzled LDS.
// In-place (outH==xH) safe: each block reads only its own 128 rows (tail clamps to N-1,
// which belongs to the last block itself), all reads precede epilogue stores.
__global__ __launch_bounds__(256) void sage_mfma_kernel(
    const ushort* __restrict__ aggH, const ushort* __restrict__ aggL,
    const ushort* xH, const ushort* xL,
    const ushort* __restrict__ WlH, const ushort* __restrict__ WlL,
    const ushort* __restrict__ WrH, const ushort* __restrict__ WrL,
    const float* __restrict__ bias,
    ushort* outH, ushort* outL, int N) {
  __shared__ ushort As[128 * 64];
  __shared__ ushort Bs[128 * 64];

  const int tid = threadIdx.x;
  const int bm = blockIdx.x * 128;
  const int wave = tid >> 6;
  const int lane = tid & 63;
  const int l15 = lane & 15;
  const int quad = lane >> 4;
  const int wm = wave >> 1;
  const int wn = wave & 1;

  f32x4 acc[4][4];
#pragma unroll
  for (int i = 0; i < 4; ++i)
#pragma unroll
    for (int j = 0; j < 4; ++j) acc[i][j] = (f32x4){0.f, 0.f, 0.f, 0.f};

  for (int it = 0; it < 12; ++it) {
    const int seg = it >> 1;
    const int kt = (it & 1) << 6;
    const ushort *Ap, *Wp;
    if (seg == 0)      { Ap = aggH; Wp = WlH; }
    else if (seg == 1) { Ap = aggL; Wp = WlH; }
    else if (seg == 2) { Ap = aggH; Wp = WlL; }
    else if (seg == 3) { Ap = xH;   Wp = WrH; }
    else if (seg == 4) { Ap = xL;   Wp = WrH; }
    else               { Ap = xH;   Wp = WrL; }
    __syncthreads();  // previous tile's reads done
#pragma unroll
    for (int c = 0; c < 4; ++c) {
      int flat = c * 256 + tid;          // 0..1023 : 128 rows x 8 kgroups of 16B
      int row = flat >> 3;
      int kg = flat & 7;
      int swz = (kg ^ (row & 7)) << 3;
      int grow = bm + row;
      if (grow >= N) grow = N - 1;
      *(int4*)(&As[row * 64 + swz]) = *(const int4*)(Ap + (size_t)grow * DIM + kt + kg * 8);
      *(int4*)(&Bs[row * 64 + swz]) = *(const int4*)(Wp + (size_t)row * DIM + kt + kg * 8);
    }
    __syncthreads();
#pragma unroll
    for (int ks = 0; ks < 2; ++ks) {
      bf16x8 af[4], bfr[4];
      int kg = (ks << 2) + quad;
#pragma unroll
      for (int i = 0; i < 4; ++i) {
        int ar = (wm << 6) + (i << 4) + l15;
        af[i] = *(const bf16x8*)(&As[ar * 64 + ((kg ^ (ar & 7)) << 3)]);
        int br = (wn << 6) + (i << 4) + l15;
        bfr[i] = *(const bf16x8*)(&Bs[br * 64 + ((kg ^ (br & 7)) << 3)]);
      }
#pragma unroll
      for (int i = 0; i < 4; ++i)
#pragma unroll
        for (int j = 0; j < 4; ++j)
          acc[i][j] = __builtin_amdgcn_mfma_f32_16x16x32_bf16(af[i], bfr[j], acc[i][j], 0, 0, 0);
    }
  }

  float bv[4];
#pragma unroll
  for (int j = 0; j < 4; ++j) bv[j] = bias[(wn << 6) + (j << 4) + l15];
#pragma unroll
  for (int i = 0; i < 4; ++i) {
#pragma unroll
    for (int r = 0; r < 4; ++r) {
      int grow = bm + (wm << 6) + (i << 4) + (quad << 2) + r;
      if (grow < N) {
#pragma unroll
        for (int j = 0; j < 4; ++j) {
          float v = fmaxf(acc[i][j][r] + bv[j], 0.f);
          ushort h = f2bf(v);
          size_t o = (size_t)grow * DIM + (wn << 6) + (j << 4) + l15;
          outH[o] = h;
          outL[o] = f2bf(v - bf2f(h));
        }
      }
    }
  }
}

// ---------------- layer 3 small GEMM from bf16 hi/lo h ----------------
__global__ __launch_bounds__(256) void lin3_kernel(const ushort* __restrict__ hH,
                                                   const ushort* __restrict__ hL,
                                                   const float* __restrict__ W3l,
                                                   const float* __restrict__ W3r,
                                                   float* __restrict__ y, int N) {
  __shared__ float Wc[DIM][4];
  int tid = threadIdx.x;
  if (tid < DIM) {
    Wc[tid][0] = W3l[tid * 2 + 0];
    Wc[tid][1] = W3l[tid * 2 + 1];
    Wc[tid][2] = W3r[tid * 2 + 0];
    Wc[tid][3] = W3r[tid * 2 + 1];
  }
  __syncthreads();
  int gid = blockIdx.x * 256 + tid;
  int n = gid >> 2, j = gid & 3;
  if (n >= N) return;
  const ushort* rH = hH + (size_t)n * DIM;
  const ushort* rL = hL + (size_t)n * DIM;
  float s = 0.f;
#pragma unroll 4
  for (int k8 = 0; k8 < 16; ++k8) {
    int4 a = *(const int4*)(rH + k8 * 8);
    int4 b = *(const int4*)(rL + k8 * 8);
    unsigned aa[4] = {(unsigned)a.x, (unsigned)a.y, (unsigned)a.z, (unsigned)a.w};
    unsigned bb[4] = {(unsigned)b.x, (unsigned)b.y, (unsigned)b.z, (unsigned)b.w};
#pragma unroll
    for (int t = 0; t < 4; ++t) {
      float h0 = __uint_as_float(aa[t] << 16) + __uint_as_float(bb[t] << 16);
      float h1 = __uint_as_float(aa[t] & 0xFFFF0000u) + __uint_as_float(bb[t] & 0xFFFF0000u);
      s += h0 * Wc[k8 * 8 + t * 2][j] + h1 * Wc[k8 * 8 + t * 2 + 1][j];
    }
  }
  y[gid] = s;
}

// ---------------- layer 3: 2-dim CSR gather + bias + relu + log_softmax ----------------
__global__ __launch_bounds__(256) void final3_kernel(const float* __restrict__ y,
                                                     const int* __restrict__ csr_src,
                                                     const unsigned* __restrict__ off,
                                                     const float* __restrict__ dinv,
                                                     const float* __restrict__ b3,
                                                     float* __restrict__ out, int N) {
  int n = blockIdx.x * 256 + threadIdx.x;
  if (n >= N) return;
  unsigned beg = off[n], end = off[n + 1];
  float s0 = 0.f, s1 = 0.f;
  for (unsigned e = beg; e < end; ++e) {
    int s = csr_src[e];
    float2 v = *reinterpret_cast<const float2*>(&y[(size_t)s * 4]);
    s0 += v.x; s1 += v.y;
  }
  float di = dinv[n];
  float o0 = fmaxf(s0 * di + y[(size_t)n * 4 + 2] + b3[0], 0.f);
  float o1 = fmaxf(s1 * di + y[(size_t)n * 4 + 3] + b3[1], 0.f);
  float m = fmaxf(o0, o1);
  float l = m + logf(expf(o0 - m) + expf(o1 - m));
  out[n * 2 + 0] = o0 - l;
  out[n * 2 + 1] = o1 - l;
}

extern "C" void kernel_launch(void* const* d_in, const int* in_sizes, int n_in,
                              void* d_out, int out_size, void* d_ws, size_t ws_size,
                              hipStream_t stream) {
  const float* x   = (const float*)d_in[0];
  const int*   ei  = (const int*)d_in[1];
  const float* W1l = (const float*)d_in[2];
  const float* W1r = (const float*)d_in[3];
  const float* b1  = (const float*)d_in[4];
  const float* W2l = (const float*)d_in[5];
  const float* W2r = (const float*)d_in[6];
  const float* b2  = (const float*)d_in[7];
  const float* W3l = (const float*)d_in[8];
  const float* W3r = (const float*)d_in[9];
  const float* b3  = (const float*)d_in[10];

  const int N = in_sizes[0] / DIM;  // 100000
  const int E = in_sizes[1] / 2;    // 1600000
  const int* src = ei;
  const int* dst = ei + E;
  const int B = (N + 255) / 256;

  char* ws = (char*)d_ws;
  size_t off_b = 0;
  auto alloc = [&](size_t bytes) {
    void* p = ws + off_b;
    off_b = (off_b + bytes + 255) & ~(size_t)255;
    return p;
  };
  unsigned* deg     = (unsigned*)alloc((size_t)N * 4);
  unsigned* excl    = (unsigned*)alloc((size_t)N * 4);  // -> cursor
  unsigned* partial = (unsigned*)alloc((size_t)B * 4);
  unsigned* offs    = (unsigned*)alloc((size_t)(N + 1) * 4);
  int*      csr_src = (int*)alloc((size_t)E * 4);
  float*    dinv    = (float*)alloc((size_t)N * 4);
  ushort*   xH      = (ushort*)alloc((size_t)N * DIM * 2);
  ushort*   xL      = (ushort*)alloc((size_t)N * DIM * 2);
  ushort*   aggH    = (ushort*)alloc((size_t)N * DIM * 2);
  ushort*   aggL    = (ushort*)alloc((size_t)N * DIM * 2);
  ushort*   wtabs   = (ushort*)alloc((size_t)8 * 16384 * 2);
  float*    y       = (float*)aggH;  // alias: agg tables dead before lin3

  // ---- CSR build ----
  hipMemsetAsync(deg, 0, (size_t)N * 4, stream);
  hist_kernel<<<(E + 255) / 256, 256, 0, stream>>>(dst, deg, E);
  dinv_kernel<<<(N + 255) / 256, 256, 0, stream>>>(deg, dinv, N);
  scan_block_kernel<<<B, 256, 0, stream>>>(deg, excl, partial, N);
  scan_partials_kernel<<<1, 256, 0, stream>>>(partial, B);
  add_offsets_kernel<<<(N + 256) / 256, 256, 0, stream>>>(excl, partial, offs, N, E);
  unsigned* cursor = excl;
  hipMemsetAsync(cursor, 0, (size_t)N * 4, stream);
  csr_fill_kernel<<<(E + 255) / 256, 256, 0, stream>>>(src, dst, offs, cursor, csr_src, E);

  // ---- precision prep ----
  split_kernel<<<(int)(((size_t)N * DIM / 4 + 255) / 256), 256, 0, stream>>>(
      x, xH, xL, (long)N * DIM);
  wsplit_kernel<<<dim3(64, 4), 256, 0, stream>>>(W1l, W1r, W2l, W2r, wtabs);
  const ushort* W1lH = wtabs;           const ushort* W1lL = wtabs + 16384;
  const ushort* W1rH = wtabs + 32768;   const ushort* W1rL = wtabs + 49152;
  const ushort* W2lH = wtabs + 65536;   const ushort* W2lL = wtabs + 81920;
  const ushort* W2rH = wtabs + 98304;   const ushort* W2rL = wtabs + 114688;

  const int gemm_grid = (N + 127) / 128;

  // ---- layer 1 (h1 written in-place over x tables) ----
  gather_bf16_kernel<<<(N + 15) / 16, 256, 0, stream>>>(xH, csr_src, offs, dinv, aggH, aggL, N);
  sage_mfma_kernel<<<gemm_grid, 256, 0, stream>>>(aggH, aggL, xH, xL, W1lH, W1lL, W1rH, W1rL,
                                                  b1, xH, xL, N);
  // ---- layer 2 (h2 in-place again) ----
  gather_bf16_kernel<<<(N + 15) / 16, 256, 0, stream>>>(xH, csr_src, offs, dinv, aggH, aggL, N);
  sage_mfma_kernel<<<gemm_grid, 256, 0, stream>>>(aggH, aggL, xH, xL, W2lH, W2lL, W2rH, W2rL,
                                                  b2, xH, xL, N);
  // ---- layer 3 ----
  lin3_kernel<<<(N * 4 + 255) / 256, 256, 0, stream>>>(xH, xL, W3l, W3r, y, N);
  final3_kernel<<<(N + 255) / 256, 256, 0, stream>>>(y, csr_src, offs, dinv, b3, (float*)d_out, N);
}

// Round 4
// 473.556 us; speedup vs baseline: 12.6888x; 1.1209x over previous
//
#include <hip/hip_runtime.h>
#include <hip/hip_bf16.h>
#include <math.h>

#define DIM 128

typedef __attribute__((ext_vector_type(8))) short bf16x8;
typedef __attribute__((ext_vector_type(4))) float f32x4;

__device__ __forceinline__ ushort f2bf(float f) {  // RTNE
  unsigned u = __float_as_uint(f);
  return (ushort)((u + 0x7FFFu + ((u >> 16) & 1u)) >> 16);
}
__device__ __forceinline__ float bf2f(ushort h) {
  return __uint_as_float(((unsigned)h) << 16);
}

// ---------------- degree histogram + per-edge rank ----------------
// atomicAdd's return value IS the edge's rank within its dst bucket.
__global__ __launch_bounds__(256) void hist_rank_kernel(const int* __restrict__ dst,
                                                        unsigned* __restrict__ deg,
                                                        unsigned* __restrict__ rank, int E) {
  int gid = blockIdx.x * 256 + threadIdx.x;
  if (gid < E) rank[gid] = atomicAdd(&deg[dst[gid]], 1u);
}

// ---------------- two-level exclusive scan over deg (+ fused dinv) ----------------
__global__ __launch_bounds__(256) void scan_block_kernel(const unsigned* __restrict__ deg,
                                                         unsigned* __restrict__ excl,
                                                         unsigned* __restrict__ partial,
                                                         float* __restrict__ dinv, int N) {
  __shared__ unsigned s[256];
  int i = blockIdx.x * 256 + threadIdx.x;
  unsigned v = (i < N) ? deg[i] : 0u;
  if (i < N) dinv[i] = 1.0f / fmaxf((float)v, 1.0f);
  s[threadIdx.x] = v;
  __syncthreads();
#pragma unroll
  for (int d = 1; d < 256; d <<= 1) {
    unsigned t = (threadIdx.x >= d) ? s[threadIdx.x - d] : 0u;
    __syncthreads();
    s[threadIdx.x] += t;
    __syncthreads();
  }
  if (i < N) excl[i] = s[threadIdx.x] - v;
  if (threadIdx.x == 255) partial[blockIdx.x] = s[255];
}

__global__ __launch_bounds__(256) void scan_partials_kernel(unsigned* __restrict__ partial, int B) {
  __shared__ unsigned s[256];
  __shared__ unsigned carry;
  if (threadIdx.x == 0) carry = 0u;
  __syncthreads();
  for (int base = 0; base < B; base += 256) {
    int i = base + threadIdx.x;
    unsigned v = (i < B) ? partial[i] : 0u;
    s[threadIdx.x] = v;
    __syncthreads();
#pragma unroll
    for (int d = 1; d < 256; d <<= 1) {
      unsigned t = (threadIdx.x >= d) ? s[threadIdx.x - d] : 0u;
      __syncthreads();
      s[threadIdx.x] += t;
      __syncthreads();
    }
    if (i < B) partial[i] = carry + s[threadIdx.x] - v;
    __syncthreads();
    if (threadIdx.x == 0) carry += s[255];
    __syncthreads();
  }
}

__global__ __launch_bounds__(256) void add_offsets_kernel(const unsigned* __restrict__ excl,
                                                          const unsigned* __restrict__ partial,
                                                          unsigned* __restrict__ off, int N, int E) {
  int i = blockIdx.x * 256 + threadIdx.x;
  if (i < N) off[i] = excl[i] + partial[i >> 8];
  if (i == N) off[N] = (unsigned)E;
}

// ---------------- CSR fill: atomic-free (rank precomputed by hist) ----------------
__global__ __launch_bounds__(256) void csr_fill_kernel(const int* __restrict__ src,
                                                       const int* __restrict__ dst,
                                                       const unsigned* __restrict__ rank,
                                                       const unsigned* __restrict__ off,
                                                       int* __restrict__ csr_src, int E) {
  int e = blockIdx.x * 256 + threadIdx.x;
  if (e >= E) return;
  csr_src[off[dst[e]] + rank[e]] = src[e];
}

// ---------------- fp32 -> bf16 hi/lo split ----------------
__global__ __launch_bounds__(256) void split_kernel(const float* __restrict__ x,
                                                    ushort* __restrict__ xh,
                                                    ushort* __restrict__ xl, long total) {
  long i = ((long)blockIdx.x * 256 + threadIdx.x) * 4;
  if (i >= total) return;
  float4 v = *(const float4*)(x + i);
  ushort h0 = f2bf(v.x), h1 = f2bf(v.y), h2 = f2bf(v.z), h3 = f2bf(v.w);
  ushort l0 = f2bf(v.x - bf2f(h0)), l1 = f2bf(v.y - bf2f(h1));
  ushort l2 = f2bf(v.z - bf2f(h2)), l3 = f2bf(v.w - bf2f(h3));
  uint2 H, L;
  H.x = (unsigned)h0 | ((unsigned)h1 << 16);
  H.y = (unsigned)h2 | ((unsigned)h3 << 16);
  L.x = (unsigned)l0 | ((unsigned)l1 << 16);
  L.y = (unsigned)l2 | ((unsigned)l3 << 16);
  *(uint2*)(xh + i) = H;
  *(uint2*)(xl + i) = L;
}

// ---------------- W fp32 [k][n] -> transposed bf16 hi/lo tables [n][k] ----------------
__global__ __launch_bounds__(256) void wsplit_kernel(const float* __restrict__ W1l,
                                                     const float* __restrict__ W1r,
                                                     const float* __restrict__ W2l,
                                                     const float* __restrict__ W2r,
                                                     ushort* __restrict__ tabs) {
  int m = blockIdx.y;
  const float* W = (m == 0) ? W1l : (m == 1) ? W1r : (m == 2) ? W2l : W2r;
  ushort* H = tabs + (size_t)m * 32768;
  ushort* L = H + 16384;
  int idx = blockIdx.x * 256 + threadIdx.x;  // 0..16383
  int k = idx >> 7, n = idx & 127;
  float v = W[idx];
  ushort h = f2bf(v);
  H[n * DIM + k] = h;
  L[n * DIM + k] = f2bf(v - bf2f(h));
}

// ---------------- gather-aggregate from bf16 hi table; emit agg hi/lo ----------------
__global__ __launch_bounds__(256) void gather_bf16_kernel(
    const ushort* __restrict__ featH, const int* __restrict__ csr_src,
    const unsigned* __restrict__ off, const float* __restrict__ dinv,
    ushort* __restrict__ aggH, ushort* __restrict__ aggL, int N) {
  int node = blockIdx.x * 16 + (threadIdx.x >> 4);
  if (node >= N) return;
  int lane = threadIdx.x & 15;
  unsigned beg = off[node], end = off[node + 1];
  float acc[8];
#pragma unroll
  for (int t = 0; t < 8; ++t) acc[t] = 0.f;
  for (unsigned e = beg; e < end; ++e) {
    int s = csr_src[e];
    int4 v = *(const int4*)(featH + (size_t)s * DIM + lane * 8);
    unsigned w0 = (unsigned)v.x, w1 = (unsigned)v.y, w2 = (unsigned)v.z, w3 = (unsigned)v.w;
    acc[0] += __uint_as_float(w0 << 16);
    acc[1] += __uint_as_float(w0 & 0xFFFF0000u);
    acc[2] += __uint_as_float(w1 << 16);
    acc[3] += __uint_as_float(w1 & 0xFFFF0000u);
    acc[4] += __uint_as_float(w2 << 16);
    acc[5] += __uint_as_float(w2 & 0xFFFF0000u);
    acc[6] += __uint_as_float(w3 << 16);
    acc[7] += __uint_as_float(w3 & 0xFFFF0000u);
  }
  float di = dinv[node];
  unsigned ph[4], pl[4];
#pragma unroll
  for (int t = 0; t < 4; ++t) {
    float f0 = acc[2 * t] * di, f1 = acc[2 * t + 1] * di;
    ushort h0 = f2bf(f0), h1 = f2bf(f1);
    ushort l0 = f2bf(f0 - bf2f(h0)), l1 = f2bf(f1 - bf2f(h1));
    ph[t] = (unsigned)h0 | ((unsigned)h1 << 16);
    pl[t] = (unsigned)l0 | ((unsigned)l1 << 16);
  }
  size_t o = (size_t)node * DIM + lane * 8;
  *(int4*)(aggH + o) = make_int4((int)ph[0], (int)ph[1], (int)ph[2], (int)ph[3]);
  *(int4*)(aggL + o) = make_int4((int)pl[0], (int)pl[1], (int)pl[2], (int)pl[3]);
}

// ---------------- MFMA SAGE layer ----------------
// out = relu( (aggH+aggL)@Wl + (xH+xL)@Wr + b ) via 6 bf16 segments (lo@lo dropped)
__global__ __launch_bounds__(256) void sage_mfma_kernel(
    const ushort* __restrict__ aggH, const ushort* __restrict__ aggL,
    const ushort* xH, const ushort* xL,
    const ushort* __restrict__ WlH, const ushort* __restrict__ WlL,
    const ushort* __restrict__ WrH, const ushort* __restrict__ WrL,
    const float* __restrict__ bias,
    ushort* outH, ushort* outL, int N) {
  __shared__ ushort As[128 * 64];
  __shared__ ushort Bs[128 * 64];

  const int tid = threadIdx.x;
  const int bm = blockIdx.x * 128;
  const int wave = tid >> 6;
  const int lane = tid & 63;
  const int l15 = lane & 15;
  const int quad = lane >> 4;
  const int wm = wave >> 1;
  const int wn = wave & 1;

  f32x4 acc[4][4];
#pragma unroll
  for (int i = 0; i < 4; ++i)
#pragma unroll
    for (int j = 0; j < 4; ++j) acc[i][j] = (f32x4){0.f, 0.f, 0.f, 0.f};

  for (int it = 0; it < 12; ++it) {
    const int seg = it >> 1;
    const int kt = (it & 1) << 6;
    const ushort *Ap, *Wp;
    if (seg == 0)      { Ap = aggH; Wp = WlH; }
    else if (seg == 1) { Ap = aggL; Wp = WlH; }
    else if (seg == 2) { Ap = aggH; Wp = WlL; }
    else if (seg == 3) { Ap = xH;   Wp = WrH; }
    else if (seg == 4) { Ap = xL;   Wp = WrH; }
    else               { Ap = xH;   Wp = WrL; }
    __syncthreads();
#pragma unroll
    for (int c = 0; c < 4; ++c) {
      int flat = c * 256 + tid;
      int row = flat >> 3;
      int kg = flat & 7;
      int swz = (kg ^ (row & 7)) << 3;
      int grow = bm + row;
      if (grow >= N) grow = N - 1;
      *(int4*)(&As[row * 64 + swz]) = *(const int4*)(Ap + (size_t)grow * DIM + kt + kg * 8);
      *(int4*)(&Bs[row * 64 + swz]) = *(const int4*)(Wp + (size_t)row * DIM + kt + kg * 8);
    }
    __syncthreads();
#pragma unroll
    for (int ks = 0; ks < 2; ++ks) {
      bf16x8 af[4], bfr[4];
      int kg = (ks << 2) + quad;
#pragma unroll
      for (int i = 0; i < 4; ++i) {
        int ar = (wm << 6) + (i << 4) + l15;
        af[i] = *(const bf16x8*)(&As[ar * 64 + ((kg ^ (ar & 7)) << 3)]);
        int br = (wn << 6) + (i << 4) + l15;
        bfr[i] = *(const bf16x8*)(&Bs[br * 64 + ((kg ^ (br & 7)) << 3)]);
      }
#pragma unroll
      for (int i = 0; i < 4; ++i)
#pragma unroll
        for (int j = 0; j < 4; ++j)
          acc[i][j] = __builtin_amdgcn_mfma_f32_16x16x32_bf16(af[i], bfr[j], acc[i][j], 0, 0, 0);
    }
  }

  float bv[4];
#pragma unroll
  for (int j = 0; j < 4; ++j) bv[j] = bias[(wn << 6) + (j << 4) + l15];
#pragma unroll
  for (int i = 0; i < 4; ++i) {
#pragma unroll
    for (int r = 0; r < 4; ++r) {
      int grow = bm + (wm << 6) + (i << 4) + (quad << 2) + r;
      if (grow < N) {
#pragma unroll
        for (int j = 0; j < 4; ++j) {
          float v = fmaxf(acc[i][j][r] + bv[j], 0.f);
          ushort h = f2bf(v);
          size_t o = (size_t)grow * DIM + (wn << 6) + (j << 4) + l15;
          outH[o] = h;
          outL[o] = f2bf(v - bf2f(h));
        }
      }
    }
  }
}

// ---------------- layer 3 small GEMM from bf16 hi/lo h ----------------
__global__ __launch_bounds__(256) void lin3_kernel(const ushort* __restrict__ hH,
                                                   const ushort* __restrict__ hL,
                                                   const float* __restrict__ W3l,
                                                   const float* __restrict__ W3r,
                                                   float* __restrict__ y, int N) {
  __shared__ float Wc[DIM][4];
  int tid = threadIdx.x;
  if (tid < DIM) {
    Wc[tid][0] = W3l[tid * 2 + 0];
    Wc[tid][1] = W3l[tid * 2 + 1];
    Wc[tid][2] = W3r[tid * 2 + 0];
    Wc[tid][3] = W3r[tid * 2 + 1];
  }
  __syncthreads();
  int gid = blockIdx.x * 256 + tid;
  int n = gid >> 2, j = gid & 3;
  if (n >= N) return;
  const ushort* rH = hH + (size_t)n * DIM;
  const ushort* rL = hL + (size_t)n * DIM;
  float s = 0.f;
#pragma unroll 4
  for (int k8 = 0; k8 < 16; ++k8) {
    int4 a = *(const int4*)(rH + k8 * 8);
    int4 b = *(const int4*)(rL + k8 * 8);
    unsigned aa[4] = {(unsigned)a.x, (unsigned)a.y, (unsigned)a.z, (unsigned)a.w};
    unsigned bb[4] = {(unsigned)b.x, (unsigned)b.y, (unsigned)b.z, (unsigned)b.w};
#pragma unroll
    for (int t = 0; t < 4; ++t) {
      float h0 = __uint_as_float(aa[t] << 16) + __uint_as_float(bb[t] << 16);
      float h1 = __uint_as_float(aa[t] & 0xFFFF0000u) + __uint_as_float(bb[t] & 0xFFFF0000u);
      s += h0 * Wc[k8 * 8 + t * 2][j] + h1 * Wc[k8 * 8 + t * 2 + 1][j];
    }
  }
  y[gid] = s;
}

// ---------------- layer 3: 2-dim CSR gather + bias + relu + log_softmax ----------------
__global__ __launch_bounds__(256) void final3_kernel(const float* __restrict__ y,
                                                     const int* __restrict__ csr_src,
                                                     const unsigned* __restrict__ off,
                                                     const float* __restrict__ dinv,
                                                     const float* __restrict__ b3,
                                                     float* __restrict__ out, int N) {
  int n = blockIdx.x * 256 + threadIdx.x;
  if (n >= N) return;
  unsigned beg = off[n], end = off[n + 1];
  float s0 = 0.f, s1 = 0.f;
  for (unsigned e = beg; e < end; ++e) {
    int s = csr_src[e];
    float2 v = *reinterpret_cast<const float2*>(&y[(size_t)s * 4]);
    s0 += v.x; s1 += v.y;
  }
  float di = dinv[n];
  float o0 = fmaxf(s0 * di + y[(size_t)n * 4 + 2] + b3[0], 0.f);
  float o1 = fmaxf(s1 * di + y[(size_t)n * 4 + 3] + b3[1], 0.f);
  float m = fmaxf(o0, o1);
  float l = m + logf(expf(o0 - m) + expf(o1 - m));
  out[n * 2 + 0] = o0 - l;
  out[n * 2 + 1] = o1 - l;
}

extern "C" void kernel_launch(void* const* d_in, const int* in_sizes, int n_in,
                              void* d_out, int out_size, void* d_ws, size_t ws_size,
                              hipStream_t stream) {
  const float* x   = (const float*)d_in[0];
  const int*   ei  = (const int*)d_in[1];
  const float* W1l = (const float*)d_in[2];
  const float* W1r = (const float*)d_in[3];
  const float* b1  = (const float*)d_in[4];
  const float* W2l = (const float*)d_in[5];
  const float* W2r = (const float*)d_in[6];
  const float* b2  = (const float*)d_in[7];
  const float* W3l = (const float*)d_in[8];
  const float* W3r = (const float*)d_in[9];
  const float* b3  = (const float*)d_in[10];

  const int N = in_sizes[0] / DIM;  // 100000
  const int E = in_sizes[1] / 2;    // 1600000
  const int* src = ei;
  const int* dst = ei + E;
  const int B = (N + 255) / 256;

  char* ws = (char*)d_ws;
  size_t off_b = 0;
  auto alloc = [&](size_t bytes) {
    void* p = ws + off_b;
    off_b = (off_b + bytes + 255) & ~(size_t)255;
    return p;
  };
  unsigned* deg     = (unsigned*)alloc((size_t)N * 4);
  unsigned* excl    = (unsigned*)alloc((size_t)N * 4);
  unsigned* partial = (unsigned*)alloc((size_t)B * 4);
  unsigned* offs    = (unsigned*)alloc((size_t)(N + 1) * 4);
  unsigned* rank    = (unsigned*)alloc((size_t)E * 4);
  int*      csr_src = (int*)alloc((size_t)E * 4);
  float*    dinv    = (float*)alloc((size_t)N * 4);
  ushort*   xH      = (ushort*)alloc((size_t)N * DIM * 2);
  ushort*   xL      = (ushort*)alloc((size_t)N * DIM * 2);
  ushort*   aggH    = (ushort*)alloc((size_t)N * DIM * 2);
  ushort*   aggL    = (ushort*)alloc((size_t)N * DIM * 2);
  ushort*   wtabs   = (ushort*)alloc((size_t)8 * 16384 * 2);
  float*    y       = (float*)aggH;  // alias: agg tables dead before lin3

  // ---- CSR build (atomic only in hist; fill is atomic-free via rank) ----
  hipMemsetAsync(deg, 0, (size_t)N * 4, stream);
  hist_rank_kernel<<<(E + 255) / 256, 256, 0, stream>>>(dst, deg, rank, E);
  scan_block_kernel<<<B, 256, 0, stream>>>(deg, excl, partial, dinv, N);
  scan_partials_kernel<<<1, 256, 0, stream>>>(partial, B);
  add_offsets_kernel<<<(N + 256) / 256, 256, 0, stream>>>(excl, partial, offs, N, E);
  csr_fill_kernel<<<(E + 255) / 256, 256, 0, stream>>>(src, dst, rank, offs, csr_src, E);

  // ---- precision prep ----
  split_kernel<<<(int)(((size_t)N * DIM / 4 + 255) / 256), 256, 0, stream>>>(
      x, xH, xL, (long)N * DIM);
  wsplit_kernel<<<dim3(64, 4), 256, 0, stream>>>(W1l, W1r, W2l, W2r, wtabs);
  const ushort* W1lH = wtabs;           const ushort* W1lL = wtabs + 16384;
  const ushort* W1rH = wtabs + 32768;   const ushort* W1rL = wtabs + 49152;
  const ushort* W2lH = wtabs + 65536;   const ushort* W2lL = wtabs + 81920;
  const ushort* W2rH = wtabs + 98304;   const ushort* W2rL = wtabs + 114688;

  const int gemm_grid = (N + 127) / 128;

  // ---- layer 1 (h1 written in-place over x tables) ----
  gather_bf16_kernel<<<(N + 15) / 16, 256, 0, stream>>>(xH, csr_src, offs, dinv, aggH, aggL, N);
  sage_mfma_kernel<<<gemm_grid, 256, 0, stream>>>(aggH, aggL, xH, xL, W1lH, W1lL, W1rH, W1rL,
                                                  b1, xH, xL, N);
  // ---- layer 2 (h2 in-place again) ----
  gather_bf16_kernel<<<(N + 15) / 16, 256, 0, stream>>>(xH, csr_src, offs, dinv, aggH, aggL, N);
  sage_mfma_kernel<<<gemm_grid, 256, 0, stream>>>(aggH, aggL, xH, xL, W2lH, W2lL, W2rH, W2rL,
                                                  b2, xH, xL, N);
  // ---- layer 3 ----
  lin3_kernel<<<(N * 4 + 255) / 256, 256, 0, stream>>>(xH, xL, W3l, W3r, y, N);
  final3_kernel<<<(N + 255) / 256, 256, 0, stream>>>(y, csr_src, offs, dinv, b3, (float*)d_out, N);
}